// Round 14
// baseline (137.124 us; speedup 1.0000x reference)
//
#include <hip/hip_runtime.h>
#include <hip/hip_bf16.h>
#include <math.h>

// ---------------------------------------------------------------------------
// AdaptivePruner: entropy-gated 1- or 2-level DWT (db4 lowpass) along tokens.
//   x: (32, 4097, 768) f32, cls_attention_map: (32, 4096) f32
//   out0: (32, 2052, 768) f32 = [cls ; lvl==1 ? y1 : pad(y2)]
//   out1: (32, 2052) bool mask (written as 0.0/1.0 f32)
// Round 14: exact R11 (best, 125.1 us) with ONE change: nontemporal stores
//           -> regular stores. NT was added blind in R2 and never isolated;
//           fillBuffer sustains 7 TB/s writes WITHOUT nt. If the nt flag was
//           degrading write-back bursts, this recovers it; if neutral, the
//           kernel is at the mixed-stream HBM floor.
// ---------------------------------------------------------------------------

typedef float f4 __attribute__((ext_vector_type(4)));

#define B_       32
#define NTOK     4097
#define NPATCH   4096
#define D_       768
#define D4_      192    // 768 / 4 channels per float4
#define L1_      2051   // (4096+7)/2, pad (6,6)
#define L2_      1029   // (2051+7)/2, pad (6,7)
#define OUTROWS  2052
#define TOUT     16
#define NTILES   129    // ceil(2051 / 16)
#define NWG      (B_ * NTILES)   // 4128, divisible by 8

// KERNEL_LO = DEC_LO reversed (JAX conv = correlation, no flip)
__device__ __constant__ float KLO[8] = {
     0.2303778133088965f,
     0.7148465705529157f,
     0.6308807679298589f,
    -0.027983769416859854f,
    -0.18703481171909309f,
     0.030841381835560764f,
     0.0328830116668852f,
    -0.010597401785069032f
};

__device__ __forceinline__ f4 dot8v(const f4 w[8]) {
    f4 a = KLO[0] * w[0];
#pragma unroll
    for (int t = 1; t < 8; ++t) {
        a.x = fmaf(KLO[t], w[t].x, a.x);
        a.y = fmaf(KLO[t], w[t].y, a.y);
        a.z = fmaf(KLO[t], w[t].z, a.z);
        a.w = fmaf(KLO[t], w[t].w, a.w);
    }
    return a;
}

// --- kernel 1: per-batch entropy (double accumulation) ----------------------
__global__ void ent_kernel(const float* __restrict__ att, double* __restrict__ ent) {
    __shared__ double sm[256];
    const int b = blockIdx.x;
    const float* a = att + (size_t)b * NPATCH;
    double acc = 0.0;
    for (int i = threadIdx.x; i < NPATCH; i += 256) {
        double v = (double)a[i];
        acc += v * log2(v + 1e-9);
    }
    sm[threadIdx.x] = acc;
    __syncthreads();
    for (int s = 128; s > 0; s >>= 1) {
        if (threadIdx.x < s) sm[threadIdx.x] += sm[threadIdx.x + s];
        __syncthreads();
    }
    if (threadIdx.x == 0) ent[b] = -sm[0];
}

// --- kernel 2: fused DWT + inline level decision + cls row + mask -----------
__global__ __launch_bounds__(192) void dwt_kernel(const f4* __restrict__ x,
                                                  const double* __restrict__ ent,
                                                  f4* __restrict__ out,
                                                  float* __restrict__ mask) {
    // Bijective XCD swizzle (NWG % 8 == 0).
    const int bid  = blockIdx.x;
    const int lid  = (bid & 7) * (NWG / 8) + (bid >> 3);
    const int b    = lid / NTILES;
    const int tile = lid % NTILES;
    const int o0   = tile * TOUT;
    const int d    = threadIdx.x;                        // float4-channel 0..191

    const f4* xb = x + (size_t)b * NTOK * D4_ + d;       // row n: xb[n*192]
    f4* ob = out + (size_t)b * OUTROWS * D4_ + d;        // row r: ob[r*192]

    const f4 z4 = (f4)(0.0f);
    // xpad[q] = x[b, 1 + (q-6), :] with zero pad outside [0, 4096)
    auto xload = [&](int q) -> f4 {
        const int n = q - 6;
        return (n >= 0 && n < NPATCH) ? xb[(size_t)(n + 1) * D4_] : z4;
    };
    // unguarded row read for interior tiles: row = (q-6)+1
    auto xrow = [&](int q) -> f4 {
        return xb[(size_t)(q - 5) * D4_];
    };

    const bool interior = (o0 >= TOUT && o0 <= 2016);
    const int q0 = 2 * o0;

    // ---- issue the L1 window loads FIRST (correct for ~93% of blocks); the
    //      stats below overlap these loads instead of blocking them.
    f4 xw[8];
    if (interior) {
#pragma unroll
        for (int t = 0; t < 8; ++t) xw[t] = xrow(q0 + t);
    } else {
#pragma unroll
        for (int t = 0; t < 8; ++t) xw[t] = xload(q0 + t);
    }

    // ---- inline stats (uniform, redundant per thread; overlaps loads above)
    double m = 0.0;
    for (int i = 0; i < B_; ++i) m += ent[i];
    m *= (1.0 / B_);
    double v = 0.0;
    for (int i = 0; i < B_; ++i) { double dd = ent[i] - m; v += dd * dd; }
    v *= (1.0 / (B_ - 1));
    const double sd = sqrt(v);
    const int L = (sd < 1e-6) ? 1 : ((ent[b] < m - 1.5 * sd) ? 2 : 1);

    if (L == 1) {
        if (interior) {
            // ---- interior fast path: all loads in-bounds, all 16 stores valid
#pragma unroll
            for (int s = 0; s < TOUT; ++s) {
                ob[(size_t)(o0 + s + 1) * D4_] = dot8v(xw);
#pragma unroll
                for (int t = 0; t < 6; ++t) xw[t] = xw[t + 2];
                xw[6] = xrow(q0 + 2 * s + 8);
                xw[7] = xrow(q0 + 2 * s + 9);
            }
        } else {
            // ---- guarded boundary path
#pragma unroll
            for (int s = 0; s < TOUT; ++s) {
                const int o = o0 + s;
                if (o < L1_) ob[(size_t)(o + 1) * D4_] = dot8v(xw);
#pragma unroll
                for (int t = 0; t < 6; ++t) xw[t] = xw[t + 2];
                xw[6] = xload(q0 + 2 * s + 8);
                xw[7] = xload(q0 + 2 * s + 9);
            }
        }
    } else {
        if (o0 >= L2_) {
            // pure zero tail tile
#pragma unroll
            for (int s = 0; s < TOUT; ++s) {
                const int o = o0 + s;
                if (o < L1_) ob[(size_t)(o + 1) * D4_] = z4;
            }
        } else if (o0 >= TOUT && o0 <= 992) {
            // ---- interior fast path: j in [0,2051), x rows in [0,4096)
            int j = 2 * o0 - 6;
#pragma unroll
            for (int t = 0; t < 8; ++t) xw[t] = xrow(2 * j + t);

            auto produceF = [&]() -> f4 {
                f4 vv = dot8v(xw);
#pragma unroll
                for (int t = 0; t < 6; ++t) xw[t] = xw[t + 2];
                xw[6] = xrow(2 * j + 8);
                xw[7] = xrow(2 * j + 9);
                ++j;
                return vv;
            };

            f4 yw[8];
#pragma unroll
            for (int t = 0; t < 8; ++t) yw[t] = produceF();
#pragma unroll
            for (int s = 0; s < TOUT; ++s) {
                ob[(size_t)(o0 + s + 1) * D4_] = dot8v(yw);
#pragma unroll
                for (int t = 0; t < 6; ++t) yw[t] = yw[t + 2];
                yw[6] = produceF();
                yw[7] = produceF();
            }
        } else {
            // ---- guarded boundary path
            int j = 2 * o0 - 6;
#pragma unroll
            for (int t = 0; t < 8; ++t) xw[t] = xload(2 * j + t);

            auto produce = [&]() -> f4 {
                f4 vv = z4;
                if (j >= 0 && j < L1_) vv = dot8v(xw);
#pragma unroll
                for (int t = 0; t < 6; ++t) xw[t] = xw[t + 2];
                xw[6] = xload(2 * j + 8);
                xw[7] = xload(2 * j + 9);
                ++j;
                return vv;
            };

            f4 yw[8];
#pragma unroll
            for (int t = 0; t < 8; ++t) yw[t] = produce();
#pragma unroll
            for (int s = 0; s < TOUT; ++s) {
                const int o = o0 + s;
                if (o < L1_) {
                    ob[(size_t)(o + 1) * D4_] = (o < L2_) ? dot8v(yw) : z4;
                }
#pragma unroll
                for (int t = 0; t < 6; ++t) yw[t] = yw[t + 2];
                yw[6] = produce();
                yw[7] = produce();
            }
        }
    }

    // ---- epilogue: cls row + mask (off the load-issue critical path)
    if (tile == 0) ob[0] = xb[0];
    {
        const int len = (L == 1) ? L1_ : L2_;
        const int o = o0 + d;
        if (d < TOUT && o < L1_)
            mask[(size_t)b * OUTROWS + o + 1] = (o < len) ? 1.0f : 0.0f;
        if (tile == 0 && d == TOUT)
            mask[(size_t)b * OUTROWS] = 1.0f;
    }
}

extern "C" void kernel_launch(void* const* d_in, const int* in_sizes, int n_in,
                              void* d_out, int out_size, void* d_ws, size_t ws_size,
                              hipStream_t stream) {
    const float* x   = (const float*)d_in[0];
    const float* att = (const float*)d_in[1];
    float* out  = (float*)d_out;
    float* mask = out + (size_t)B_ * OUTROWS * D_;

    double* ent = (double*)d_ws;

    ent_kernel<<<B_, 256, 0, stream>>>(att, ent);
    dwt_kernel<<<NWG, 192, 0, stream>>>((const f4*)x, ent, (f4*)out, mask);
}

// Round 15
// 133.746 us; speedup vs baseline: 1.0253x; 1.0253x over previous
//
#include <hip/hip_runtime.h>
#include <hip/hip_bf16.h>
#include <math.h>

// ---------------------------------------------------------------------------
// AdaptivePruner: entropy-gated 1- or 2-level DWT (db4 lowpass) along tokens.
//   x: (32, 4097, 768) f32, cls_attention_map: (32, 4096) f32
//   out0: (32, 2052, 768) f32 = [cls ; lvl==1 ? y1 : pad(y2)]
//   out1: (32, 2052) bool mask (written as 0.0/1.0 f32)
// Round 15: exact R11 (best, 125.1 us; NT stores PROVEN +12 us by R14's
//           regression) + ONE change: x loads become nontemporal too.
//           Both streams are touch-once; nt keeps them from allocating L2,
//           freeing L2 entirely (halo re-reads fall back to L3, not HBM).
// ---------------------------------------------------------------------------

typedef float f4 __attribute__((ext_vector_type(4)));

#define B_       32
#define NTOK     4097
#define NPATCH   4096
#define D_       768
#define D4_      192    // 768 / 4 channels per float4
#define L1_      2051   // (4096+7)/2, pad (6,6)
#define L2_      1029   // (2051+7)/2, pad (6,7)
#define OUTROWS  2052
#define TOUT     16
#define NTILES   129    // ceil(2051 / 16)
#define NWG      (B_ * NTILES)   // 4128, divisible by 8

// KERNEL_LO = DEC_LO reversed (JAX conv = correlation, no flip)
__device__ __constant__ float KLO[8] = {
     0.2303778133088965f,
     0.7148465705529157f,
     0.6308807679298589f,
    -0.027983769416859854f,
    -0.18703481171909309f,
     0.030841381835560764f,
     0.0328830116668852f,
    -0.010597401785069032f
};

__device__ __forceinline__ f4 dot8v(const f4 w[8]) {
    f4 a = KLO[0] * w[0];
#pragma unroll
    for (int t = 1; t < 8; ++t) {
        a.x = fmaf(KLO[t], w[t].x, a.x);
        a.y = fmaf(KLO[t], w[t].y, a.y);
        a.z = fmaf(KLO[t], w[t].z, a.z);
        a.w = fmaf(KLO[t], w[t].w, a.w);
    }
    return a;
}

// --- kernel 1: per-batch entropy (double accumulation) ----------------------
__global__ void ent_kernel(const float* __restrict__ att, double* __restrict__ ent) {
    __shared__ double sm[256];
    const int b = blockIdx.x;
    const float* a = att + (size_t)b * NPATCH;
    double acc = 0.0;
    for (int i = threadIdx.x; i < NPATCH; i += 256) {
        double v = (double)a[i];
        acc += v * log2(v + 1e-9);
    }
    sm[threadIdx.x] = acc;
    __syncthreads();
    for (int s = 128; s > 0; s >>= 1) {
        if (threadIdx.x < s) sm[threadIdx.x] += sm[threadIdx.x + s];
        __syncthreads();
    }
    if (threadIdx.x == 0) ent[b] = -sm[0];
}

// --- kernel 2: fused DWT + inline level decision + cls row + mask -----------
__global__ __launch_bounds__(192) void dwt_kernel(const f4* __restrict__ x,
                                                  const double* __restrict__ ent,
                                                  f4* __restrict__ out,
                                                  float* __restrict__ mask) {
    // Bijective XCD swizzle (NWG % 8 == 0).
    const int bid  = blockIdx.x;
    const int lid  = (bid & 7) * (NWG / 8) + (bid >> 3);
    const int b    = lid / NTILES;
    const int tile = lid % NTILES;
    const int o0   = tile * TOUT;
    const int d    = threadIdx.x;                        // float4-channel 0..191

    const f4* xb = x + (size_t)b * NTOK * D4_ + d;       // row n: xb[n*192]
    f4* ob = out + (size_t)b * OUTROWS * D4_ + d;        // row r: ob[r*192]

    const f4 z4 = (f4)(0.0f);
    // xpad[q] = x[b, 1 + (q-6), :] with zero pad outside [0, 4096)  (nt loads)
    auto xload = [&](int q) -> f4 {
        const int n = q - 6;
        return (n >= 0 && n < NPATCH)
            ? __builtin_nontemporal_load(&xb[(size_t)(n + 1) * D4_]) : z4;
    };
    // unguarded row read for interior tiles: row = (q-6)+1
    auto xrow = [&](int q) -> f4 {
        return __builtin_nontemporal_load(&xb[(size_t)(q - 5) * D4_]);
    };

    const bool interior = (o0 >= TOUT && o0 <= 2016);
    const int q0 = 2 * o0;

    // ---- issue the L1 window loads FIRST (correct for ~93% of blocks); the
    //      stats below overlap these loads instead of blocking them.
    f4 xw[8];
    if (interior) {
#pragma unroll
        for (int t = 0; t < 8; ++t) xw[t] = xrow(q0 + t);
    } else {
#pragma unroll
        for (int t = 0; t < 8; ++t) xw[t] = xload(q0 + t);
    }

    // ---- inline stats (uniform, redundant per thread; overlaps loads above)
    double m = 0.0;
    for (int i = 0; i < B_; ++i) m += ent[i];
    m *= (1.0 / B_);
    double v = 0.0;
    for (int i = 0; i < B_; ++i) { double dd = ent[i] - m; v += dd * dd; }
    v *= (1.0 / (B_ - 1));
    const double sd = sqrt(v);
    const int L = (sd < 1e-6) ? 1 : ((ent[b] < m - 1.5 * sd) ? 2 : 1);

    if (L == 1) {
        if (interior) {
            // ---- interior fast path: all loads in-bounds, all 16 stores valid
#pragma unroll
            for (int s = 0; s < TOUT; ++s) {
                __builtin_nontemporal_store(dot8v(xw), &ob[(size_t)(o0 + s + 1) * D4_]);
#pragma unroll
                for (int t = 0; t < 6; ++t) xw[t] = xw[t + 2];
                xw[6] = xrow(q0 + 2 * s + 8);
                xw[7] = xrow(q0 + 2 * s + 9);
            }
        } else {
            // ---- guarded boundary path
#pragma unroll
            for (int s = 0; s < TOUT; ++s) {
                const int o = o0 + s;
                if (o < L1_) __builtin_nontemporal_store(dot8v(xw), &ob[(size_t)(o + 1) * D4_]);
#pragma unroll
                for (int t = 0; t < 6; ++t) xw[t] = xw[t + 2];
                xw[6] = xload(q0 + 2 * s + 8);
                xw[7] = xload(q0 + 2 * s + 9);
            }
        }
    } else {
        if (o0 >= L2_) {
            // pure zero tail tile
#pragma unroll
            for (int s = 0; s < TOUT; ++s) {
                const int o = o0 + s;
                if (o < L1_) __builtin_nontemporal_store(z4, &ob[(size_t)(o + 1) * D4_]);
            }
        } else if (o0 >= TOUT && o0 <= 992) {
            // ---- interior fast path: j in [0,2051), x rows in [0,4096)
            int j = 2 * o0 - 6;
#pragma unroll
            for (int t = 0; t < 8; ++t) xw[t] = xrow(2 * j + t);

            auto produceF = [&]() -> f4 {
                f4 vv = dot8v(xw);
#pragma unroll
                for (int t = 0; t < 6; ++t) xw[t] = xw[t + 2];
                xw[6] = xrow(2 * j + 8);
                xw[7] = xrow(2 * j + 9);
                ++j;
                return vv;
            };

            f4 yw[8];
#pragma unroll
            for (int t = 0; t < 8; ++t) yw[t] = produceF();
#pragma unroll
            for (int s = 0; s < TOUT; ++s) {
                __builtin_nontemporal_store(dot8v(yw), &ob[(size_t)(o0 + s + 1) * D4_]);
#pragma unroll
                for (int t = 0; t < 6; ++t) yw[t] = yw[t + 2];
                yw[6] = produceF();
                yw[7] = produceF();
            }
        } else {
            // ---- guarded boundary path
            int j = 2 * o0 - 6;
#pragma unroll
            for (int t = 0; t < 8; ++t) xw[t] = xload(2 * j + t);

            auto produce = [&]() -> f4 {
                f4 vv = z4;
                if (j >= 0 && j < L1_) vv = dot8v(xw);
#pragma unroll
                for (int t = 0; t < 6; ++t) xw[t] = xw[t + 2];
                xw[6] = xload(2 * j + 8);
                xw[7] = xload(2 * j + 9);
                ++j;
                return vv;
            };

            f4 yw[8];
#pragma unroll
            for (int t = 0; t < 8; ++t) yw[t] = produce();
#pragma unroll
            for (int s = 0; s < TOUT; ++s) {
                const int o = o0 + s;
                if (o < L1_) {
                    f4 vv = (o < L2_) ? dot8v(yw) : z4;
                    __builtin_nontemporal_store(vv, &ob[(size_t)(o + 1) * D4_]);
                }
#pragma unroll
                for (int t = 0; t < 6; ++t) yw[t] = yw[t + 2];
                yw[6] = produce();
                yw[7] = produce();
            }
        }
    }

    // ---- epilogue: cls row + mask (off the load-issue critical path)
    if (tile == 0) ob[0] = __builtin_nontemporal_load(&xb[0]);
    {
        const int len = (L == 1) ? L1_ : L2_;
        const int o = o0 + d;
        if (d < TOUT && o < L1_)
            mask[(size_t)b * OUTROWS + o + 1] = (o < len) ? 1.0f : 0.0f;
        if (tile == 0 && d == TOUT)
            mask[(size_t)b * OUTROWS] = 1.0f;
    }
}

extern "C" void kernel_launch(void* const* d_in, const int* in_sizes, int n_in,
                              void* d_out, int out_size, void* d_ws, size_t ws_size,
                              hipStream_t stream) {
    const float* x   = (const float*)d_in[0];
    const float* att = (const float*)d_in[1];
    float* out  = (float*)d_out;
    float* mask = out + (size_t)B_ * OUTROWS * D_;

    double* ent = (double*)d_ws;

    ent_kernel<<<B_, 256, 0, stream>>>(att, ent);
    dwt_kernel<<<NWG, 192, 0, stream>>>((const f4*)x, ent, (f4*)out, mask);
}

// Round 16
// 122.302 us; speedup vs baseline: 1.1212x; 1.0936x over previous
//
#include <hip/hip_runtime.h>
#include <hip/hip_bf16.h>
#include <math.h>

// ---------------------------------------------------------------------------
// AdaptivePruner: entropy-gated 1- or 2-level DWT (db4 lowpass) along tokens.
//   x: (32, 4097, 768) f32, cls_attention_map: (32, 4096) f32
//   out0: (32, 2052, 768) f32 = [cls ; lvl==1 ? y1 : pad(y2)]
//   out1: (32, 2052) bool mask (written as 0.0/1.0 f32)
// Round 16: exact R11 (champion, 125.1 us: NT stores proven +12 us by R14,
//           regular loads proven +9 us vs NT loads by R15) + ONE change:
//           ent_kernel uses HW __log2f (v_log_f32) + double accumulation
//           instead of softfloat double log2 (validated R12/R13; never
//           banked standalone).
// ---------------------------------------------------------------------------

typedef float f4 __attribute__((ext_vector_type(4)));

#define B_       32
#define NTOK     4097
#define NPATCH   4096
#define D_       768
#define D4_      192    // 768 / 4 channels per float4
#define L1_      2051   // (4096+7)/2, pad (6,6)
#define L2_      1029   // (2051+7)/2, pad (6,7)
#define OUTROWS  2052
#define TOUT     16
#define NTILES   129    // ceil(2051 / 16)
#define NWG      (B_ * NTILES)   // 4128, divisible by 8

// KERNEL_LO = DEC_LO reversed (JAX conv = correlation, no flip)
__device__ __constant__ float KLO[8] = {
     0.2303778133088965f,
     0.7148465705529157f,
     0.6308807679298589f,
    -0.027983769416859854f,
    -0.18703481171909309f,
     0.030841381835560764f,
     0.0328830116668852f,
    -0.010597401785069032f
};

__device__ __forceinline__ f4 dot8v(const f4 w[8]) {
    f4 a = KLO[0] * w[0];
#pragma unroll
    for (int t = 1; t < 8; ++t) {
        a.x = fmaf(KLO[t], w[t].x, a.x);
        a.y = fmaf(KLO[t], w[t].y, a.y);
        a.z = fmaf(KLO[t], w[t].z, a.z);
        a.w = fmaf(KLO[t], w[t].w, a.w);
    }
    return a;
}

// --- kernel 1: per-batch entropy (f32 HW log2, double accumulation) ---------
__global__ void ent_kernel(const float* __restrict__ att, double* __restrict__ ent) {
    __shared__ double sm[256];
    const int b = blockIdx.x;
    const float* a = att + (size_t)b * NPATCH;
    double acc = 0.0;
    for (int i = threadIdx.x; i < NPATCH; i += 256) {
        const float v = a[i];
        acc += (double)(v * __log2f(v + 1e-9f));
    }
    sm[threadIdx.x] = acc;
    __syncthreads();
    for (int s = 128; s > 0; s >>= 1) {
        if (threadIdx.x < s) sm[threadIdx.x] += sm[threadIdx.x + s];
        __syncthreads();
    }
    if (threadIdx.x == 0) ent[b] = -sm[0];
}

// --- kernel 2: fused DWT + inline level decision + cls row + mask -----------
__global__ __launch_bounds__(192) void dwt_kernel(const f4* __restrict__ x,
                                                  const double* __restrict__ ent,
                                                  f4* __restrict__ out,
                                                  float* __restrict__ mask) {
    // Bijective XCD swizzle (NWG % 8 == 0).
    const int bid  = blockIdx.x;
    const int lid  = (bid & 7) * (NWG / 8) + (bid >> 3);
    const int b    = lid / NTILES;
    const int tile = lid % NTILES;
    const int o0   = tile * TOUT;
    const int d    = threadIdx.x;                        // float4-channel 0..191

    const f4* xb = x + (size_t)b * NTOK * D4_ + d;       // row n: xb[n*192]
    f4* ob = out + (size_t)b * OUTROWS * D4_ + d;        // row r: ob[r*192]

    const f4 z4 = (f4)(0.0f);
    // xpad[q] = x[b, 1 + (q-6), :] with zero pad outside [0, 4096)
    auto xload = [&](int q) -> f4 {
        const int n = q - 6;
        return (n >= 0 && n < NPATCH) ? xb[(size_t)(n + 1) * D4_] : z4;
    };
    // unguarded row read for interior tiles: row = (q-6)+1
    auto xrow = [&](int q) -> f4 {
        return xb[(size_t)(q - 5) * D4_];
    };

    const bool interior = (o0 >= TOUT && o0 <= 2016);
    const int q0 = 2 * o0;

    // ---- issue the L1 window loads FIRST (correct for ~93% of blocks); the
    //      stats below overlap these loads instead of blocking them.
    f4 xw[8];
    if (interior) {
#pragma unroll
        for (int t = 0; t < 8; ++t) xw[t] = xrow(q0 + t);
    } else {
#pragma unroll
        for (int t = 0; t < 8; ++t) xw[t] = xload(q0 + t);
    }

    // ---- inline stats (uniform, redundant per thread; overlaps loads above)
    double m = 0.0;
    for (int i = 0; i < B_; ++i) m += ent[i];
    m *= (1.0 / B_);
    double v = 0.0;
    for (int i = 0; i < B_; ++i) { double dd = ent[i] - m; v += dd * dd; }
    v *= (1.0 / (B_ - 1));
    const double sd = sqrt(v);
    const int L = (sd < 1e-6) ? 1 : ((ent[b] < m - 1.5 * sd) ? 2 : 1);

    if (L == 1) {
        if (interior) {
            // ---- interior fast path: all loads in-bounds, all 16 stores valid
#pragma unroll
            for (int s = 0; s < TOUT; ++s) {
                __builtin_nontemporal_store(dot8v(xw), &ob[(size_t)(o0 + s + 1) * D4_]);
#pragma unroll
                for (int t = 0; t < 6; ++t) xw[t] = xw[t + 2];
                xw[6] = xrow(q0 + 2 * s + 8);
                xw[7] = xrow(q0 + 2 * s + 9);
            }
        } else {
            // ---- guarded boundary path
#pragma unroll
            for (int s = 0; s < TOUT; ++s) {
                const int o = o0 + s;
                if (o < L1_) __builtin_nontemporal_store(dot8v(xw), &ob[(size_t)(o + 1) * D4_]);
#pragma unroll
                for (int t = 0; t < 6; ++t) xw[t] = xw[t + 2];
                xw[6] = xload(q0 + 2 * s + 8);
                xw[7] = xload(q0 + 2 * s + 9);
            }
        }
    } else {
        if (o0 >= L2_) {
            // pure zero tail tile
#pragma unroll
            for (int s = 0; s < TOUT; ++s) {
                const int o = o0 + s;
                if (o < L1_) __builtin_nontemporal_store(z4, &ob[(size_t)(o + 1) * D4_]);
            }
        } else if (o0 >= TOUT && o0 <= 992) {
            // ---- interior fast path: j in [0,2051), x rows in [0,4096)
            int j = 2 * o0 - 6;
#pragma unroll
            for (int t = 0; t < 8; ++t) xw[t] = xrow(2 * j + t);

            auto produceF = [&]() -> f4 {
                f4 vv = dot8v(xw);
#pragma unroll
                for (int t = 0; t < 6; ++t) xw[t] = xw[t + 2];
                xw[6] = xrow(2 * j + 8);
                xw[7] = xrow(2 * j + 9);
                ++j;
                return vv;
            };

            f4 yw[8];
#pragma unroll
            for (int t = 0; t < 8; ++t) yw[t] = produceF();
#pragma unroll
            for (int s = 0; s < TOUT; ++s) {
                __builtin_nontemporal_store(dot8v(yw), &ob[(size_t)(o0 + s + 1) * D4_]);
#pragma unroll
                for (int t = 0; t < 6; ++t) yw[t] = yw[t + 2];
                yw[6] = produceF();
                yw[7] = produceF();
            }
        } else {
            // ---- guarded boundary path
            int j = 2 * o0 - 6;
#pragma unroll
            for (int t = 0; t < 8; ++t) xw[t] = xload(2 * j + t);

            auto produce = [&]() -> f4 {
                f4 vv = z4;
                if (j >= 0 && j < L1_) vv = dot8v(xw);
#pragma unroll
                for (int t = 0; t < 6; ++t) xw[t] = xw[t + 2];
                xw[6] = xload(2 * j + 8);
                xw[7] = xload(2 * j + 9);
                ++j;
                return vv;
            };

            f4 yw[8];
#pragma unroll
            for (int t = 0; t < 8; ++t) yw[t] = produce();
#pragma unroll
            for (int s = 0; s < TOUT; ++s) {
                const int o = o0 + s;
                if (o < L1_) {
                    f4 vv = (o < L2_) ? dot8v(yw) : z4;
                    __builtin_nontemporal_store(vv, &ob[(size_t)(o + 1) * D4_]);
                }
#pragma unroll
                for (int t = 0; t < 6; ++t) yw[t] = yw[t + 2];
                yw[6] = produce();
                yw[7] = produce();
            }
        }
    }

    // ---- epilogue: cls row + mask (off the load-issue critical path)
    if (tile == 0) ob[0] = xb[0];
    {
        const int len = (L == 1) ? L1_ : L2_;
        const int o = o0 + d;
        if (d < TOUT && o < L1_)
            mask[(size_t)b * OUTROWS + o + 1] = (o < len) ? 1.0f : 0.0f;
        if (tile == 0 && d == TOUT)
            mask[(size_t)b * OUTROWS] = 1.0f;
    }
}

extern "C" void kernel_launch(void* const* d_in, const int* in_sizes, int n_in,
                              void* d_out, int out_size, void* d_ws, size_t ws_size,
                              hipStream_t stream) {
    const float* x   = (const float*)d_in[0];
    const float* att = (const float*)d_in[1];
    float* out  = (float*)d_out;
    float* mask = out + (size_t)B_ * OUTROWS * D_;

    double* ent = (double*)d_ws;

    ent_kernel<<<B_, 256, 0, stream>>>(att, ent);
    dwt_kernel<<<NWG, 192, 0, stream>>>((const f4*)x, ent, (f4*)out, mask);
}

// Round 17
// 118.519 us; speedup vs baseline: 1.1570x; 1.0319x over previous
//
#include <hip/hip_runtime.h>
#include <hip/hip_bf16.h>
#include <math.h>

// ---------------------------------------------------------------------------
// AdaptivePruner: entropy-gated 1- or 2-level DWT (db4 lowpass) along tokens.
//   x: (32, 4097, 768) f32, cls_attention_map: (32, 4096) f32
//   out0: (32, 2052, 768) f32 = [cls ; lvl==1 ? y1 : pad(y2)]
//   out1: (32, 2052) bool mask (written as 0.0/1.0 f32)
// Round 17: exact R16 (champion 122.3 us: NT stores, regular loads, __log2f
//           ent, inline stats, interior fast paths) + ONE change: TOUT 16->8
//           (8224 blocks). 4128 blocks = 1.6 scheduling generations/CU ->
//           ragged final generation ~25% of a generation idle; 8224 = 3.2
//           generations -> tail ~6%. Halo overfetch rises but is cache-
//           absorbed (R13/R15 evidence: never reaches HBM).
// ---------------------------------------------------------------------------

typedef float f4 __attribute__((ext_vector_type(4)));

#define B_       32
#define NTOK     4097
#define NPATCH   4096
#define D_       768
#define D4_      192    // 768 / 4 channels per float4
#define L1_      2051   // (4096+7)/2, pad (6,6)
#define L2_      1029   // (2051+7)/2, pad (6,7)
#define OUTROWS  2052
#define TOUT     8
#define NTILES   257    // ceil(2051 / 8) = 257 (256.375 -> 257)
#define NWG      (B_ * NTILES)   // 8224, divisible by 8

// KERNEL_LO = DEC_LO reversed (JAX conv = correlation, no flip)
__device__ __constant__ float KLO[8] = {
     0.2303778133088965f,
     0.7148465705529157f,
     0.6308807679298589f,
    -0.027983769416859854f,
    -0.18703481171909309f,
     0.030841381835560764f,
     0.0328830116668852f,
    -0.010597401785069032f
};

__device__ __forceinline__ f4 dot8v(const f4 w[8]) {
    f4 a = KLO[0] * w[0];
#pragma unroll
    for (int t = 1; t < 8; ++t) {
        a.x = fmaf(KLO[t], w[t].x, a.x);
        a.y = fmaf(KLO[t], w[t].y, a.y);
        a.z = fmaf(KLO[t], w[t].z, a.z);
        a.w = fmaf(KLO[t], w[t].w, a.w);
    }
    return a;
}

// --- kernel 1: per-batch entropy (f32 HW log2, double accumulation) ---------
__global__ void ent_kernel(const float* __restrict__ att, double* __restrict__ ent) {
    __shared__ double sm[256];
    const int b = blockIdx.x;
    const float* a = att + (size_t)b * NPATCH;
    double acc = 0.0;
    for (int i = threadIdx.x; i < NPATCH; i += 256) {
        const float v = a[i];
        acc += (double)(v * __log2f(v + 1e-9f));
    }
    sm[threadIdx.x] = acc;
    __syncthreads();
    for (int s = 128; s > 0; s >>= 1) {
        if (threadIdx.x < s) sm[threadIdx.x] += sm[threadIdx.x + s];
        __syncthreads();
    }
    if (threadIdx.x == 0) ent[b] = -sm[0];
}

// --- kernel 2: fused DWT + inline level decision + cls row + mask -----------
__global__ __launch_bounds__(192) void dwt_kernel(const f4* __restrict__ x,
                                                  const double* __restrict__ ent,
                                                  f4* __restrict__ out,
                                                  float* __restrict__ mask) {
    // Bijective XCD swizzle (NWG % 8 == 0).
    const int bid  = blockIdx.x;
    const int lid  = (bid & 7) * (NWG / 8) + (bid >> 3);
    const int b    = lid / NTILES;
    const int tile = lid % NTILES;
    const int o0   = tile * TOUT;
    const int d    = threadIdx.x;                        // float4-channel 0..191

    const f4* xb = x + (size_t)b * NTOK * D4_ + d;       // row n: xb[n*192]
    f4* ob = out + (size_t)b * OUTROWS * D4_ + d;        // row r: ob[r*192]

    const f4 z4 = (f4)(0.0f);
    // xpad[q] = x[b, 1 + (q-6), :] with zero pad outside [0, 4096)
    auto xload = [&](int q) -> f4 {
        const int n = q - 6;
        return (n >= 0 && n < NPATCH) ? xb[(size_t)(n + 1) * D4_] : z4;
    };
    // unguarded row read for interior tiles: row = (q-6)+1
    auto xrow = [&](int q) -> f4 {
        return xb[(size_t)(q - 5) * D4_];
    };

    const bool interior = (o0 >= TOUT && o0 + TOUT <= 2048);
    const int q0 = 2 * o0;

    // ---- issue the L1 window loads FIRST (correct for ~93% of blocks); the
    //      stats below overlap these loads instead of blocking them.
    f4 xw[8];
    if (interior) {
#pragma unroll
        for (int t = 0; t < 8; ++t) xw[t] = xrow(q0 + t);
    } else {
#pragma unroll
        for (int t = 0; t < 8; ++t) xw[t] = xload(q0 + t);
    }

    // ---- inline stats (uniform, redundant per thread; overlaps loads above)
    double m = 0.0;
    for (int i = 0; i < B_; ++i) m += ent[i];
    m *= (1.0 / B_);
    double v = 0.0;
    for (int i = 0; i < B_; ++i) { double dd = ent[i] - m; v += dd * dd; }
    v *= (1.0 / (B_ - 1));
    const double sd = sqrt(v);
    const int L = (sd < 1e-6) ? 1 : ((ent[b] < m - 1.5 * sd) ? 2 : 1);

    if (L == 1) {
        if (interior) {
            // ---- interior fast path: all loads in-bounds, all stores valid
#pragma unroll
            for (int s = 0; s < TOUT; ++s) {
                __builtin_nontemporal_store(dot8v(xw), &ob[(size_t)(o0 + s + 1) * D4_]);
#pragma unroll
                for (int t = 0; t < 6; ++t) xw[t] = xw[t + 2];
                xw[6] = xrow(q0 + 2 * s + 8);
                xw[7] = xrow(q0 + 2 * s + 9);
            }
        } else {
            // ---- guarded boundary path
#pragma unroll
            for (int s = 0; s < TOUT; ++s) {
                const int o = o0 + s;
                if (o < L1_) __builtin_nontemporal_store(dot8v(xw), &ob[(size_t)(o + 1) * D4_]);
#pragma unroll
                for (int t = 0; t < 6; ++t) xw[t] = xw[t + 2];
                xw[6] = xload(q0 + 2 * s + 8);
                xw[7] = xload(q0 + 2 * s + 9);
            }
        }
    } else {
        if (o0 >= L2_) {
            // pure zero tail tile
#pragma unroll
            for (int s = 0; s < TOUT; ++s) {
                const int o = o0 + s;
                if (o < L1_) __builtin_nontemporal_store(z4, &ob[(size_t)(o + 1) * D4_]);
            }
        } else if (o0 >= TOUT && o0 + TOUT <= 1024) {
            // ---- interior fast path: j in [0,2051), x rows in [0,4096)
            int j = 2 * o0 - 6;
#pragma unroll
            for (int t = 0; t < 8; ++t) xw[t] = xrow(2 * j + t);

            auto produceF = [&]() -> f4 {
                f4 vv = dot8v(xw);
#pragma unroll
                for (int t = 0; t < 6; ++t) xw[t] = xw[t + 2];
                xw[6] = xrow(2 * j + 8);
                xw[7] = xrow(2 * j + 9);
                ++j;
                return vv;
            };

            f4 yw[8];
#pragma unroll
            for (int t = 0; t < 8; ++t) yw[t] = produceF();
#pragma unroll
            for (int s = 0; s < TOUT; ++s) {
                __builtin_nontemporal_store(dot8v(yw), &ob[(size_t)(o0 + s + 1) * D4_]);
#pragma unroll
                for (int t = 0; t < 6; ++t) yw[t] = yw[t + 2];
                yw[6] = produceF();
                yw[7] = produceF();
            }
        } else {
            // ---- guarded boundary path
            int j = 2 * o0 - 6;
#pragma unroll
            for (int t = 0; t < 8; ++t) xw[t] = xload(2 * j + t);

            auto produce = [&]() -> f4 {
                f4 vv = z4;
                if (j >= 0 && j < L1_) vv = dot8v(xw);
#pragma unroll
                for (int t = 0; t < 6; ++t) xw[t] = xw[t + 2];
                xw[6] = xload(2 * j + 8);
                xw[7] = xload(2 * j + 9);
                ++j;
                return vv;
            };

            f4 yw[8];
#pragma unroll
            for (int t = 0; t < 8; ++t) yw[t] = produce();
#pragma unroll
            for (int s = 0; s < TOUT; ++s) {
                const int o = o0 + s;
                if (o < L1_) {
                    f4 vv = (o < L2_) ? dot8v(yw) : z4;
                    __builtin_nontemporal_store(vv, &ob[(size_t)(o + 1) * D4_]);
                }
#pragma unroll
                for (int t = 0; t < 6; ++t) yw[t] = yw[t + 2];
                yw[6] = produce();
                yw[7] = produce();
            }
        }
    }

    // ---- epilogue: cls row + mask (off the load-issue critical path)
    if (tile == 0) ob[0] = xb[0];
    {
        const int len = (L == 1) ? L1_ : L2_;
        const int o = o0 + d;
        if (d < TOUT && o < L1_)
            mask[(size_t)b * OUTROWS + o + 1] = (o < len) ? 1.0f : 0.0f;
        if (tile == 0 && d == TOUT)
            mask[(size_t)b * OUTROWS] = 1.0f;
    }
}

extern "C" void kernel_launch(void* const* d_in, const int* in_sizes, int n_in,
                              void* d_out, int out_size, void* d_ws, size_t ws_size,
                              hipStream_t stream) {
    const float* x   = (const float*)d_in[0];
    const float* att = (const float*)d_in[1];
    float* out  = (float*)d_out;
    float* mask = out + (size_t)B_ * OUTROWS * D_;

    double* ent = (double*)d_ws;

    ent_kernel<<<B_, 256, 0, stream>>>(att, ent);
    dwt_kernel<<<NWG, 192, 0, stream>>>((const f4*)x, ent, (f4*)out, mask);
}